// Round 7
// baseline (652.505 us; speedup 1.0000x reference)
//
#include <hip/hip_runtime.h>
#include <hip/hip_bf16.h>
#include <cstdint>

// Problem constants (fixed by the reference)
constexpr int  KDIM  = 4096;    // D_IN
constexpr int  NDIM  = 4096;    // D_OUT
constexpr long MDIM  = 16384;   // B*S
constexpr int  RANK_ = 16;
constexpr float SCALE_ = 2.0f;  // alpha/rank

constexpr int BK = 64;
constexpr int NT = KDIM / BK;   // 64 K-tiles

using bf16x8  = __attribute__((ext_vector_type(8))) short;
using f32x4   = __attribute__((ext_vector_type(4))) float;
using f32x16  = __attribute__((ext_vector_type(16))) float;

__device__ __forceinline__ void gload_lds16(const void* g, void* l) {
  __builtin_amdgcn_global_load_lds(
      (const __attribute__((address_space(1))) void*)g,
      (__attribute__((address_space(3))) void*)l, 16, 0, 0);
}

__device__ __forceinline__ unsigned short f2bf(float f) {
  union { float f; unsigned u; } v; v.f = f;
  unsigned r = v.u + 0x7FFFu + ((v.u >> 16) & 1u);
  return (unsigned short)(r >> 16);
}

// ---------------------------------------------------------------------------
// Kernel 1: W' = bf16( W + SCALE * lora_B @ lora_A )   [NDIM][KDIM]
// ---------------------------------------------------------------------------
__global__ __launch_bounds__(256) void prep_w_kernel(
    const float* __restrict__ W, const float* __restrict__ lA,
    const float* __restrict__ lB, unsigned short* __restrict__ Wp) {
  const long total8 = (long)NDIM * KDIM / 8;
  for (long t = blockIdx.x * (long)blockDim.x + threadIdx.x; t < total8;
       t += (long)gridDim.x * blockDim.x) {
    const int o  = (int)(t / (KDIM / 8));
    const int d8 = (int)(t % (KDIM / 8)) * 8;
    const float4* w4 = reinterpret_cast<const float4*>(W + (size_t)o * KDIM + d8);
    float4 w0 = w4[0], w1 = w4[1];
    float acc[8] = {w0.x, w0.y, w0.z, w0.w, w1.x, w1.y, w1.z, w1.w};
#pragma unroll
    for (int r = 0; r < RANK_; ++r) {
      const float br = SCALE_ * lB[o * RANK_ + r];
      const float4* a4 = reinterpret_cast<const float4*>(lA + (size_t)r * KDIM + d8);
      float4 a0 = a4[0], a1 = a4[1];
      acc[0] += br * a0.x; acc[1] += br * a0.y; acc[2] += br * a0.z; acc[3] += br * a0.w;
      acc[4] += br * a1.x; acc[5] += br * a1.y; acc[6] += br * a1.z; acc[7] += br * a1.w;
    }
    uint4 o4;
    o4.x = (unsigned)f2bf(acc[0]) | ((unsigned)f2bf(acc[1]) << 16);
    o4.y = (unsigned)f2bf(acc[2]) | ((unsigned)f2bf(acc[3]) << 16);
    o4.z = (unsigned)f2bf(acc[4]) | ((unsigned)f2bf(acc[5]) << 16);
    o4.w = (unsigned)f2bf(acc[6]) | ((unsigned)f2bf(acc[7]) << 16);
    *reinterpret_cast<uint4*>(Wp + t * 8) = o4;
  }
}

// ---------------------------------------------------------------------------
// Kernel 2: xb = bf16(x)   [MDIM][KDIM]
// ---------------------------------------------------------------------------
__global__ __launch_bounds__(256) void conv_x_kernel(
    const float* __restrict__ x, unsigned short* __restrict__ xb) {
  const long total8 = MDIM * KDIM / 8;
  for (long t = blockIdx.x * (long)blockDim.x + threadIdx.x; t < total8;
       t += (long)gridDim.x * blockDim.x) {
    const float4* p = reinterpret_cast<const float4*>(x + t * 8);
    float4 a = p[0], b = p[1];
    uint4 o4;
    o4.x = (unsigned)f2bf(a.x) | ((unsigned)f2bf(a.y) << 16);
    o4.y = (unsigned)f2bf(a.z) | ((unsigned)f2bf(a.w) << 16);
    o4.z = (unsigned)f2bf(b.x) | ((unsigned)f2bf(b.y) << 16);
    o4.w = (unsigned)f2bf(b.z) | ((unsigned)f2bf(b.w) << 16);
    *reinterpret_cast<uint4*>(xb + t * 8) = o4;
  }
}

// ---------------------------------------------------------------------------
// Kernel 3: 256x256 tile, 32x32x16 MFMA, 4 phases/K-tile, phase-ahead reads.
//   Per wave (2Mx4N grid): 128x64 output = 4 m-tiles x 2 n-tiles of 32x32.
//   K-tile 64 = 4 k-steps of 16. 32 MFMA/wave/K-tile (was 64 of 16x16).
//     P1: read w n0+n1 (8); stage A0(t+1); Q0 = m01 x n0; bar
//     P2: read x m23 (8);   stage A1(t+1); Q1 = m01 x n1; bar
//     P3: (no reads)        stage B0(t+2); Q2 = m23 x n1; bar
//     P4: stage B1(t+2); vmcnt(4); bar; read x m01(t+1) (8); Q3 = m23 x n0
//   Swapped operands: mfma(A=W-frag, B=x-frag); D: C-row = base+(lane&31),
//   C-cols in 4 groups of 4 at g*8 + (lane>>5)*4  -> dwordx4 stores.
// ---------------------------------------------------------------------------
__global__ __launch_bounds__(512, 2) void gemm256_kernel(
    const unsigned short* __restrict__ A,   // [MDIM][KDIM] bf16 bits (x)
    const unsigned short* __restrict__ Bm,  // [NDIM][KDIM] bf16 bits (W')
    const float* __restrict__ bias,
    float* __restrict__ C) {
  __shared__ __align__(16) unsigned char lds[131072];

  const int tid  = threadIdx.x;
  const int wave = tid >> 6, lane = tid & 63;
  const int wm = wave >> 2, wn = wave & 3;       // 2 x 4 wave grid
  const int l31 = lane & 31, h2 = lane >> 5;
  const int lrB = (wn & 1) * 64;

  // XCD-aware bijective blockIdx swizzle, R4 orientation (verified lower fetch)
  const int orig = blockIdx.x;
  const int bid  = (orig & 7) * 128 + (orig >> 3);
  const int bcol = (bid & 15) * 256;             // N-tile
  const int brow = (bid >> 4) * 256;             // M-tile

  // staging geometry (verified R2): linear LDS dest + inverse-swizzled source
  const int st_row = wave * 16 + (lane >> 2);                     // 0..127
  const int st_col = ((lane & 3) * 8) ^ (((lane >> 5) & 1) << 4); // elem [0,32)
  const unsigned short* Asrc = A  + (size_t)(brow + st_row) * KDIM + st_col;
  const unsigned short* Bsrc = Bm + (size_t)(bcol + st_row) * KDIM + st_col;

  // stage half-tile s (0=B0,1=B1,2=A0,3=A1) of K-tile tau into buffer `base`
  auto stageHalf = [&](unsigned char* base, int s, int tau) {
    const unsigned short* g = (s >= 2 ? Asrc + (size_t)(s - 2) * 128 * KDIM
                                      : Bsrc + (size_t)s * 128 * KDIM) + tau * BK;
    unsigned char* d = base + (wave << 10) + s * 16384;
    gload_lds16(g,      d);            // kk0 (k 0..31)
    gload_lds16(g + 32, d + 8192);     // kk1 (k 32..63)
  };

  // read one 32x32x16 MFMA fragment (16B/lane): row = lrow (32 rows via l31),
  // k-step ks (16 elems): byte = (ks>>1)*8192 + lrow*64 + ((ks&1)*32 + h2*16)
  // XOR the verified st_16x32 swizzle bit (row bit3 -> byte bit5).
  auto ldfrag = [&](const unsigned char* half, int lrow, int ks) -> bf16x8 {
    const int swz = ((lrow >> 3) & 1) << 5;
    return *reinterpret_cast<const bf16x8*>(
        half + (ks >> 1) * 8192 + lrow * 64 + ((((ks & 1) << 5) + (h2 << 4)) ^ swz));
  };

  f32x16 acc[4][2];
#pragma unroll
  for (int mt = 0; mt < 4; ++mt)
#pragma unroll
    for (int nt = 0; nt < 2; ++nt)
#pragma unroll
      for (int e = 0; e < 16; ++e) acc[mt][nt][e] = 0.f;

  unsigned char* const buf0 = lds;
  unsigned char* const buf1 = lds + 65536;

  // prologue: tile0 full (buf0) + tile1 B0,B1 (buf1); vmcnt(4) retires tile0,
  // leaves B(1) in flight = steady-state invariant.
  stageHalf(buf0, 0, 0); stageHalf(buf0, 1, 0);
  stageHalf(buf0, 2, 0); stageHalf(buf0, 3, 0);
  stageHalf(buf1, 0, 1); stageHalf(buf1, 1, 1);
  asm volatile("s_waitcnt vmcnt(4)" ::: "memory");
  __builtin_amdgcn_s_barrier();

  bf16x8 w0[4], w1[4], xA[2][4], xB[2][4];
  // boundary pre-read for tile 0: x m0,m1 (all 4 k-steps) from buf0
#pragma unroll
  for (int mi = 0; mi < 2; ++mi)
#pragma unroll
    for (int ks = 0; ks < 4; ++ks)
      xA[mi][ks] = ldfrag(buf0 + (2 + wm) * 16384, mi * 32 + l31, ks);

  // One K-tile: CUR = this tile's buffer, NXT = other buffer, t = tile index.
#define KTILE(CUR, NXT, t)                                                     \
  {                                                                            \
    const unsigned char* Ah  = (CUR) + (2 + wm) * 16384;                       \
    const unsigned char* Bh  = (CUR) + (wn >> 1) * 16384;                      \
    const unsigned char* AhN = (NXT) + (2 + wm) * 16384;                       \
    /* P1: read w n0 then n1 (8); stage A0(t+1); Q0 = m01 x n0; bar */         \
    _Pragma("unroll")                                                          \
    for (int ks = 0; ks < 4; ++ks) w0[ks] = ldfrag(Bh, lrB + l31, ks);         \
    _Pragma("unroll")                                                          \
    for (int ks = 0; ks < 4; ++ks) w1[ks] = ldfrag(Bh, lrB + 32 + l31, ks);    \
    if ((t) + 1 < NT) stageHalf((NXT), 2, (t) + 1);                            \
    __builtin_amdgcn_s_setprio(1);                                             \
    _Pragma("unroll")                                                          \
    for (int ks = 0; ks < 4; ++ks)                                             \
      _Pragma("unroll")                                                        \
      for (int mi = 0; mi < 2; ++mi)                                           \
        acc[mi][0] = __builtin_amdgcn_mfma_f32_32x32x16_bf16(                  \
            w0[ks], xA[mi][ks], acc[mi][0], 0, 0, 0);                          \
    __builtin_amdgcn_s_setprio(0);                                             \
    __builtin_amdgcn_s_barrier();                                              \
    /* P2: read x m23 (8); stage A1(t+1); Q1 = m01 x n1; bar */                \
    _Pragma("unroll")                                                          \
    for (int mi = 0; mi < 2; ++mi)                                             \
      _Pragma("unroll")                                                        \
      for (int ks = 0; ks < 4; ++ks)                                           \
        xB[mi][ks] = ldfrag(Ah, 64 + mi * 32 + l31, ks);                       \
    if ((t) + 1 < NT) stageHalf((NXT), 3, (t) + 1);                            \
    __builtin_amdgcn_s_setprio(1);                                             \
    _Pragma("unroll")                                                          \
    for (int ks = 0; ks < 4; ++ks)                                             \
      _Pragma("unroll")                                                        \
      for (int mi = 0; mi < 2; ++mi)                                           \
        acc[mi][1] = __builtin_amdgcn_mfma_f32_32x32x16_bf16(                  \
            w1[ks], xA[mi][ks], acc[mi][1], 0, 0, 0);                          \
    __builtin_amdgcn_s_setprio(0);                                             \
    __builtin_amdgcn_s_barrier();                                              \
    /* P3: no reads; stage B0(t+2) into CUR; Q2 = m23 x n1; bar */             \
    if ((t) + 2 < NT) stageHalf((CUR), 0, (t) + 2);                            \
    __builtin_amdgcn_s_setprio(1);                                             \
    _Pragma("unroll")                                                          \
    for (int ks = 0; ks < 4; ++ks)                                             \
      _Pragma("unroll")                                                        \
      for (int mi = 0; mi < 2; ++mi)                                           \
        acc[2 + mi][1] = __builtin_amdgcn_mfma_f32_32x32x16_bf16(              \
            w1[ks], xB[mi][ks], acc[2 + mi][1], 0, 0, 0);                      \
    __builtin_amdgcn_s_setprio(0);                                             \
    __builtin_amdgcn_s_barrier();                                              \
    /* P4: stage B1(t+2); counted vmcnt; bar; read x m01(t+1); Q3 = m23xn0 */  \
    if ((t) + 2 < NT) stageHalf((CUR), 1, (t) + 2);                            \
    if ((t) < NT - 2)       asm volatile("s_waitcnt vmcnt(4)" ::: "memory");   \
    else if ((t) == NT - 2) asm volatile("s_waitcnt vmcnt(0)" ::: "memory");   \
    __builtin_amdgcn_s_barrier();                                              \
    if ((t) + 1 < NT) {                                                        \
      _Pragma("unroll")                                                        \
      for (int mi = 0; mi < 2; ++mi)                                           \
        _Pragma("unroll")                                                      \
        for (int ks = 0; ks < 4; ++ks)                                         \
          xA[mi][ks] = ldfrag(AhN, mi * 32 + l31, ks);                         \
    }                                                                          \
    __builtin_amdgcn_s_setprio(1);                                             \
    _Pragma("unroll")                                                          \
    for (int ks = 0; ks < 4; ++ks)                                             \
      _Pragma("unroll")                                                        \
      for (int mi = 0; mi < 2; ++mi)                                           \
        acc[2 + mi][0] = __builtin_amdgcn_mfma_f32_32x32x16_bf16(              \
            w0[ks], xB[mi][ks], acc[2 + mi][0], 0, 0, 0);                      \
    __builtin_amdgcn_s_setprio(0);                                             \
  }

  for (int tt = 0; tt < NT; tt += 2) {
    KTILE(buf0, buf1, tt);
    KTILE(buf1, buf0, tt + 1);
  }
#undef KTILE

  // epilogue: 32x32 C/D layout (m74/m101), swapped operands ->
  //   C-row = brow + wm*128 + mt*32 + (lane&31)
  //   C-col = bcol + wn*64 + nt*32 + g*8 + (lane>>5)*4 + j, reg = g*4+j
#pragma unroll
  for (int mt = 0; mt < 4; ++mt) {
    const size_t row = (size_t)brow + wm * 128 + mt * 32 + l31;
#pragma unroll
    for (int nt = 0; nt < 2; ++nt) {
#pragma unroll
      for (int g = 0; g < 4; ++g) {
        const int colb = bcol + wn * 64 + nt * 32 + g * 8 + h2 * 4;
        const f32x4 bv = *reinterpret_cast<const f32x4*>(&bias[colb]);
        f32x4 v = {acc[mt][nt][g * 4 + 0], acc[mt][nt][g * 4 + 1],
                   acc[mt][nt][g * 4 + 2], acc[mt][nt][g * 4 + 3]};
        v = v + bv;
        *reinterpret_cast<f32x4*>(&C[row * NDIM + colb]) = v;
      }
    }
  }
}

// ---------------------------------------------------------------------------
extern "C" void kernel_launch(void* const* d_in, const int* in_sizes, int n_in,
                              void* d_out, int out_size, void* d_ws, size_t ws_size,
                              hipStream_t stream) {
  const float* x  = (const float*)d_in[0];   // [4,4096,4096]
  const float* W  = (const float*)d_in[1];   // [4096,4096]
  const float* b  = (const float*)d_in[2];   // [4096]
  const float* lA = (const float*)d_in[3];   // [16,4096]
  const float* lB = (const float*)d_in[4];   // [4096,16]
  float* out = (float*)d_out;                // [4,4096,4096] fp32

  unsigned short* xb = (unsigned short*)d_ws;
  unsigned short* Wp = (unsigned short*)((char*)d_ws + (size_t)MDIM * KDIM * 2);

  conv_x_kernel<<<2048, 256, 0, stream>>>(x, xb);
  prep_w_kernel<<<2048, 256, 0, stream>>>(W, lA, lB, Wp);

  gemm256_kernel<<<1024, 512, 0, stream>>>(xb, Wp, b, out);
}